// Round 2
// baseline (546.497 us; speedup 1.0000x reference)
//
#include <hip/hip_runtime.h>

// Eikonal 2D: |grad u| = f, u(256,256)=0, Godunov upwind, converged fixed point.
//
// v2 (resubmit; round-1 container failure was infra — no deadlock possible:
// no inter-block waits, fixed iteration count, bounded µs runtime).
//
// Latency-bound fix over v1 (4 cells/thread, 1 wave/SIMD, VALUBusy 48%,
// ~1200 cy/barrier-iteration fully exposed): 2 cells/thread horizontal
// pairs, 32x16 tiles, 512 blocks = 2 blocks/CU -> 8 waves/CU (2/SIMD); the
// two co-resident blocks are NOT barrier-coupled so they interleave through
// each other's barrier/halo stalls.
//
// Horizontal neighbors via DPP row_shr:1 / row_shl:1 (16 pairs of a tile row
// = one 16-lane DPP row; invalid edge lane returns the `old` operand, which
// we set to the halo register -> edge handling is free). Two GS substeps per
// barrier iteration (substep B DPP-reads post-substep-A neighbor values,
// legal in wave lockstep) give horizontal propagation >=2 cols/iter both
// directions (4/iter rightward, 2/iter leftward). Vertical stays 1/iter via
// LDS. Budget ROUNDS*KIN = 896 vs worst dependency chain ~256+256/2 = 384
// (+turn quantization) -> ~1.8x margin, same as proven v1 schedule (KIN=16
// == tile height -> no steady-state crossing waste). Monotone min-updates
// from BIG keep racy/stale halo reads harmless; under-convergence would
// leave 1e10 cells (loudly caught).

#define NG     512
#define TILEW  32
#define TILEH  16
#define BIGV   1e10f
#define SRC_I  256
#define SRC_J  256
#define KIN    16
#define ROUNDS 56

// lane i gets lane i-1's x within each 16-lane DPP row; row-lane 0 (tx==0,
// tile left edge) keeps `edge` (bound_ctrl=false -> invalid src = old).
__device__ __forceinline__ float dpp_shr1(float x, float edge) {
    return __int_as_float(__builtin_amdgcn_update_dpp(
        __float_as_int(edge), __float_as_int(x), 0x111, 0xf, 0xf, false));
}
// lane i gets lane i+1's x; row-lane 15 (tx==15, tile right edge) keeps edge.
__device__ __forceinline__ float dpp_shl1(float x, float edge) {
    return __int_as_float(__builtin_amdgcn_update_dpp(
        __float_as_int(edge), __float_as_int(x), 0x101, 0xf, 0xf, false));
}

__global__ void eik_init(float* __restrict__ u) {
    int idx = blockIdx.x * blockDim.x + threadIdx.x;
    if (idx < NG * NG) u[idx] = (idx == SRC_I * NG + SRC_J) ? 0.0f : BIGV;
}

__global__ __launch_bounds__(256, 2) void eik_persist(const float* __restrict__ f,
                                                      float* __restrict__ u) {
    __shared__ __align__(16) float S[TILEH][TILEW];   // 2 KB, interior only

    const int tx = threadIdx.x;          // pair index 0..15 (fast dim: DPP row)
    const int ty = threadIdx.y;          // row 0..15
    const int c0 = 2 * tx;
    const int gi = blockIdx.y * TILEH + ty;
    const int gj = blockIdx.x * TILEW + c0;
    const int base = gi * NG + gj;

    const float2 f2 = *(const float2*)(f + base);
    const float fh0 = f2.x, fh1 = f2.y;
    const float fq0 = 2.0f * fh0 * fh0, fq1 = 2.0f * fh1 * fh1;

    float v0 = (gi == SRC_I && gj     == SRC_J) ? 0.0f : BIGV;
    float v1 = (gi == SRC_I && gj + 1 == SRC_J) ? 0.0f : BIGV;

    const bool etop = (ty == 0), ebot = (ty == TILEH - 1);
    const bool elft = (tx == 0), ergt = (tx == 15);
    const bool hast = (gi > 0),  hasb = (gi < NG - 1);
    const bool hasl = (gj > 0),  hasr = (gj + 2 < NG);

    // clamped LDS row indices (clamped lanes' reads are discarded by selects)
    const int rup = etop ? 0 : ty - 1;
    const int rdn = ebot ? TILEH - 1 : ty + 1;

    *(float2*)&S[ty][c0] = make_float2(v0, v1);
    __syncthreads();

    for (int r = 0; r < ROUNDS; ++r) {
        // --- halo refresh (device scope; per-XCD L2s not coherent) ---
        float hN0 = BIGV, hN1 = BIGV, hS0 = BIGV, hS1 = BIGV, hW = BIGV, hE = BIGV;
        if (etop && hast) {
            hN0 = __hip_atomic_load(u + base - NG,     __ATOMIC_RELAXED, __HIP_MEMORY_SCOPE_AGENT);
            hN1 = __hip_atomic_load(u + base - NG + 1, __ATOMIC_RELAXED, __HIP_MEMORY_SCOPE_AGENT);
        }
        if (ebot && hasb) {
            hS0 = __hip_atomic_load(u + base + NG,     __ATOMIC_RELAXED, __HIP_MEMORY_SCOPE_AGENT);
            hS1 = __hip_atomic_load(u + base + NG + 1, __ATOMIC_RELAXED, __HIP_MEMORY_SCOPE_AGENT);
        }
        if (elft && hasl) hW = __hip_atomic_load(u + base - 1, __ATOMIC_RELAXED, __HIP_MEMORY_SCOPE_AGENT);
        if (ergt && hasr) hE = __hip_atomic_load(u + base + 2, __ATOMIC_RELAXED, __HIP_MEMORY_SCOPE_AGENT);

        // --- KIN barrier-separated iterations, 2 GS substeps each ---
        for (int it = 0; it < KIN; ++it) {
            const float2 uu = *(const float2*)&S[rup][c0];
            const float2 dd = *(const float2*)&S[rdn][c0];
            const float up0 = etop ? hN0 : uu.x;
            const float up1 = etop ? hN1 : uu.y;
            const float dn0 = ebot ? hS0 : dd.x;
            const float dn1 = ebot ? hS1 : dd.y;

            auto upd = [&](float& vv, float au, float ad, float lf, float rt,
                           float fh_, float fq_) {
                float a  = fminf(au, ad);
                float b  = fminf(lf, rt);
                float d  = fabsf(a - b);
                float u1 = fminf(a, b) + fh_;                 // 1D update
                float t  = fmaxf(fmaf(-d, d, fq_), 0.0f);     // 2fh^2 - d^2
                float u2 = 0.5f * (a + b) + 0.5f * sqrtf(t);  // 2D root
                float un = (d >= fh_) ? u1 : u2;              // branch-free
                vv = fminf(vv, un);                           // source stays 0
            };

            // substep A: prev-iteration horizontal neighbors
            float lfe = dpp_shr1(v1, hW);   // left pair's v1 (or hW at edge)
            float rte = dpp_shl1(v0, hE);   // right pair's v0 (or hE at edge)
            upd(v0, up0, dn0, lfe, v1, fh0, fq0);
            upd(v1, up1, dn1, v0, rte, fh1, fq1);
            // substep B: post-A neighbors via DPP (wave lockstep)
            lfe = dpp_shr1(v1, hW);
            rte = dpp_shl1(v0, hE);
            upd(v0, up0, dn0, lfe, v1, fh0, fq0);
            upd(v1, up1, dn1, v0, rte, fh1, fq1);

            *(float2*)&S[ty][c0] = make_float2(v0, v1);
            __syncthreads();   // LDS visibility + keeps propagation bound tight
        }

        // --- publish tile edges (device scope) ---
        if (etop || ebot) {
            __hip_atomic_store(u + base,     v0, __ATOMIC_RELAXED, __HIP_MEMORY_SCOPE_AGENT);
            __hip_atomic_store(u + base + 1, v1, __ATOMIC_RELAXED, __HIP_MEMORY_SCOPE_AGENT);
        }
        if (elft) __hip_atomic_store(u + base,     v0, __ATOMIC_RELAXED, __HIP_MEMORY_SCOPE_AGENT);
        if (ergt) __hip_atomic_store(u + base + 1, v1, __ATOMIC_RELAXED, __HIP_MEMORY_SCOPE_AGENT);
    }

    // final write: agent-scope b32 stores so same-address ordering with the
    // published edge stores is guaranteed (no L2-path vs LLC-path race)
    __hip_atomic_store(u + base,     v0, __ATOMIC_RELAXED, __HIP_MEMORY_SCOPE_AGENT);
    __hip_atomic_store(u + base + 1, v1, __ATOMIC_RELAXED, __HIP_MEMORY_SCOPE_AGENT);
}

extern "C" void kernel_launch(void* const* d_in, const int* in_sizes, int n_in,
                              void* d_out, int out_size, void* d_ws, size_t ws_size,
                              hipStream_t stream) {
    const float* f = (const float*)d_in[0];
    float* u = (float*)d_out;   // solution buffer + halo-exchange medium

    eik_init<<<(NG * NG + 1023) / 1024, 1024, 0, stream>>>(u);

    dim3 grid(NG / TILEW, NG / TILEH);   // (16, 32) = 512 blocks = 2/CU
    dim3 block(16, 16);                  // 256 threads = 4 waves, 2 cells/thread
    eik_persist<<<grid, block, 0, stream>>>(f, u);
}

// Round 3
// 262.884 us; speedup vs baseline: 2.0789x; 2.0789x over previous
//
#include <hip/hip_runtime.h>

// Eikonal 2D: |grad u| = f, u(256,256)=0, Godunov upwind, converged fixed point.
//
// v3: v2 went VALU-issue-bound (VALUBusy 83%, occupancy fix worked but 2 GS
// substeps/iter doubled work per cell). This version keeps the occupancy
// structure (2 cells/thread horizontal pairs, 32x16 tiles, 512 blocks =
// 2 un-coupled blocks/CU = 8 waves/CU) and halves the VALU stream:
//  - single GS substep per iteration, direction alternating per iteration
//    (rightward iters move info 2 cols right / 1 left; leftward mirrored;
//    sustained 1.5 cols/iter each way),
//  - halo rows staged into LDS once per round (S has TILEH+2 rows) so the
//    inner loop has zero edge selects,
//  - raw v_sqrt_f32 (__builtin_amdgcn_sqrtf) instead of libm sqrtf's IEEE
//    refinement sequence; -d*d folded into fma with abs modifiers.
// W/E halos stay in registers; DPP row_shr/row_shl edge lanes return the
// `old` operand = halo register, so horizontal edges are free.
//
// Budget: ROUNDS*KIN = 832 iters vs dependency chain ~(256 vert @1/iter +
// 171 horiz @1.5/iter) * ~1.3 staleness/quantization ~= 555 -> 1.5x margin.
// Monotone min-updates from BIG keep racy/stale halo reads harmless;
// under-convergence leaves 1e10 cells (loudly caught by absmax).

#define NG     512
#define TILEW  32
#define TILEH  16
#define BIGV   1e10f
#define SRC_I  256
#define SRC_J  256
#define KIN    16
#define ROUNDS 52

// lane i gets lane i-1's x within each 16-lane DPP row; row-lane 0 (tx==0,
// tile left edge) keeps `edge` (bound_ctrl=false -> invalid src = old).
__device__ __forceinline__ float dpp_shr1(float x, float edge) {
    return __int_as_float(__builtin_amdgcn_update_dpp(
        __float_as_int(edge), __float_as_int(x), 0x111, 0xf, 0xf, false));
}
// lane i gets lane i+1's x; row-lane 15 (tx==15, tile right edge) keeps edge.
__device__ __forceinline__ float dpp_shl1(float x, float edge) {
    return __int_as_float(__builtin_amdgcn_update_dpp(
        __float_as_int(edge), __float_as_int(x), 0x101, 0xf, 0xf, false));
}

__global__ void eik_init(float* __restrict__ u) {
    int idx = blockIdx.x * blockDim.x + threadIdx.x;
    if (idx < NG * NG) u[idx] = (idx == SRC_I * NG + SRC_J) ? 0.0f : BIGV;
}

__global__ __launch_bounds__(256, 2) void eik_persist(const float* __restrict__ f,
                                                      float* __restrict__ u) {
    // rows 0 and TILEH+1 are the N/S halo rows, refreshed once per round
    __shared__ __align__(16) float S[TILEH + 2][TILEW];   // 2.25 KB

    const int tx = threadIdx.x;          // pair index 0..15 (fast dim: DPP row)
    const int ty = threadIdx.y;          // row 0..15
    const int c0 = 2 * tx;
    const int gi = blockIdx.y * TILEH + ty;
    const int gj = blockIdx.x * TILEW + c0;
    const int base = gi * NG + gj;

    const float2 f2 = *(const float2*)(f + base);
    const float fh0 = f2.x, fh1 = f2.y;
    const float fq0 = 2.0f * fh0 * fh0, fq1 = 2.0f * fh1 * fh1;

    float v0 = (gi == SRC_I && gj     == SRC_J) ? 0.0f : BIGV;
    float v1 = (gi == SRC_I && gj + 1 == SRC_J) ? 0.0f : BIGV;

    const bool etop = (ty == 0), ebot = (ty == TILEH - 1);
    const bool elft = (tx == 0), ergt = (tx == 15);
    const bool hast = (gi > 0),  hasb = (gi < NG - 1);
    const bool hasl = (gj > 0),  hasr = (gj + 2 < NG);

    *(float2*)&S[ty + 1][c0] = make_float2(v0, v1);

    auto upd = [&](float& vv, float au, float ad, float lf, float rt,
                   float fh_, float fq_) {
        float a  = fminf(au, ad);
        float b  = fminf(lf, rt);
        float s  = a - b;
        float u1 = fminf(a, b) + fh_;                              // 1D update
        float t  = fmaxf(fmaf(-fabsf(s), fabsf(s), fq_), 0.0f);    // 2fh^2 - d^2
        float u2 = fmaf(0.5f, __builtin_amdgcn_sqrtf(t), 0.5f * (a + b));
        float un = (fabsf(s) >= fh_) ? u1 : u2;                    // branch-free
        vv = fminf(vv, un);                                        // src stays 0
    };

    for (int r = 0; r < ROUNDS; ++r) {
        // --- halo refresh (device scope; per-XCD L2s not coherent) ---
        float hW = BIGV, hE = BIGV;
        if (etop) {
            float hN0 = BIGV, hN1 = BIGV;
            if (hast) {
                hN0 = __hip_atomic_load(u + base - NG,     __ATOMIC_RELAXED, __HIP_MEMORY_SCOPE_AGENT);
                hN1 = __hip_atomic_load(u + base - NG + 1, __ATOMIC_RELAXED, __HIP_MEMORY_SCOPE_AGENT);
            }
            S[0][c0]     = hN0;
            S[0][c0 + 1] = hN1;
        }
        if (ebot) {
            float hS0 = BIGV, hS1 = BIGV;
            if (hasb) {
                hS0 = __hip_atomic_load(u + base + NG,     __ATOMIC_RELAXED, __HIP_MEMORY_SCOPE_AGENT);
                hS1 = __hip_atomic_load(u + base + NG + 1, __ATOMIC_RELAXED, __HIP_MEMORY_SCOPE_AGENT);
            }
            S[TILEH + 1][c0]     = hS0;
            S[TILEH + 1][c0 + 1] = hS1;
        }
        if (elft && hasl) hW = __hip_atomic_load(u + base - 1, __ATOMIC_RELAXED, __HIP_MEMORY_SCOPE_AGENT);
        if (ergt && hasr) hE = __hip_atomic_load(u + base + 2, __ATOMIC_RELAXED, __HIP_MEMORY_SCOPE_AGENT);
        __syncthreads();   // halo rows visible before first inner iteration

        // --- KIN barrier-separated iterations, alternating GS direction ---
        for (int it = 0; it < KIN; it += 2) {
            {   // rightward: lfe -> v0 -> v1 (2 cols right, 1 left)
                const float2 uu = *(const float2*)&S[ty][c0];
                const float2 dd = *(const float2*)&S[ty + 2][c0];
                float lfe = dpp_shr1(v1, hW);
                float rte = dpp_shl1(v0, hE);
                upd(v0, uu.x, dd.x, lfe, v1, fh0, fq0);
                upd(v1, uu.y, dd.y, v0, rte, fh1, fq1);
                *(float2*)&S[ty + 1][c0] = make_float2(v0, v1);
                __syncthreads();
            }
            {   // leftward: rte -> v1 -> v0 (2 cols left, 1 right)
                const float2 uu = *(const float2*)&S[ty][c0];
                const float2 dd = *(const float2*)&S[ty + 2][c0];
                float lfe = dpp_shr1(v1, hW);
                float rte = dpp_shl1(v0, hE);
                upd(v1, uu.y, dd.y, v0, rte, fh1, fq1);
                upd(v0, uu.x, dd.x, lfe, v1, fh0, fq0);
                *(float2*)&S[ty + 1][c0] = make_float2(v0, v1);
                __syncthreads();
            }
        }

        // --- publish tile edges (device scope) ---
        if (etop || ebot) {
            __hip_atomic_store(u + base,     v0, __ATOMIC_RELAXED, __HIP_MEMORY_SCOPE_AGENT);
            __hip_atomic_store(u + base + 1, v1, __ATOMIC_RELAXED, __HIP_MEMORY_SCOPE_AGENT);
        }
        if (elft) __hip_atomic_store(u + base,     v0, __ATOMIC_RELAXED, __HIP_MEMORY_SCOPE_AGENT);
        if (ergt) __hip_atomic_store(u + base + 1, v1, __ATOMIC_RELAXED, __HIP_MEMORY_SCOPE_AGENT);
    }

    // final write: agent-scope b32 stores so same-address ordering with the
    // published edge stores is guaranteed (no L2-path vs LLC-path race)
    __hip_atomic_store(u + base,     v0, __ATOMIC_RELAXED, __HIP_MEMORY_SCOPE_AGENT);
    __hip_atomic_store(u + base + 1, v1, __ATOMIC_RELAXED, __HIP_MEMORY_SCOPE_AGENT);
}

extern "C" void kernel_launch(void* const* d_in, const int* in_sizes, int n_in,
                              void* d_out, int out_size, void* d_ws, size_t ws_size,
                              hipStream_t stream) {
    const float* f = (const float*)d_in[0];
    float* u = (float*)d_out;   // solution buffer + halo-exchange medium

    eik_init<<<(NG * NG + 1023) / 1024, 1024, 0, stream>>>(u);

    dim3 grid(NG / TILEW, NG / TILEH);   // (16, 32) = 512 blocks = 2/CU
    dim3 block(16, 16);                  // 256 threads = 4 waves, 2 cells/thread
    eik_persist<<<grid, block, 0, stream>>>(f, u);
}